// Round 14
// baseline (5988.853 us; speedup 1.0000x reference)
//
#include <hip/hip_runtime.h>
#include <stdint.h>

// Persistent-LSTM, round 14: speculative validated h-read (tagged u32 data),
// fire-and-forget producer, cheap-tag-gated retry. Reverts r13's LDS-staged
// release (regressed).
//  - 256 WGs x 128 threads (2 waves). g = bid&3 (rows 16g..16g+15, XCD-pair
//    locality), m = bid>>2 (u-cols 8m..8m+7, 32 z-cols, 2 nt tiles).
//  - hbuf: tagged u32 [2][64][512], word = ((t)<<16 | bf16(h_t)). The tag IS
//    the validation: consumer loads h SPECULATIVELY before the x phase
//    (fully overlapped) and validates embedded tags after the natural
//    vmcnt(0) drain -> common case exposes ZERO exchange RTT.
//  - Producer publishes tagged h FIRE-AND-FORGET (no ack, no tag hop in its
//    serial chain). Ordering is enforced by consumer validation, not by
//    store->tag sequencing (the 2-hop design paid ack + data-RTT per step).
//  - Retry path (stale tags): poll spread cheap-tag lines (tags[4][64][16],
//    1 line/producer, 256 B/wave/round -- r9's 8 MB/round churn fix), then
//    reload once (guaranteed fresh). Cheap tag t is stored at the START of
//    iteration t, after the vmcnt(0) drain proves our h_t stores reached
//    IF$ -- off the fast path.
//  - Deadlock-free: data stores unconditional; cheap tag precedes validation
//    each iteration; entering iteration t needs only steps < t.
//  - WAR safety: tag-(t+2) overwrite of the t-parity slot requires all WGs
//    validated (consumed) h_t -- induction as r4..r13.
//  - Keeps: XCD-pair mapping (r9), nontemporal out (r9), scattered per-
//    thread stores (r13's coalescing regressed), perm repack (r9).

#define Tt   1024
#define Uu   512
#define G4U  2048
#define NWG  256
#define NTHR 128
#define TAGSTRIDE 16                               // u32s per tag line (64 B)

#define WF_ELEMS (2 * 24 * 64 * 8)                 // 24576 bf16 = 48 KB
#define WF_BYTES (WF_ELEMS * 2)
#define ZB_PLANE (16 * 17)                         // padded 16x16 f32 tile
#define SMEM_BYTES (WF_BYTES + 4 * ZB_PLANE * 4)   // 48 KB + 4352 B

typedef short  bf16x8 __attribute__((ext_vector_type(8)));
typedef float  f32x4  __attribute__((ext_vector_type(4)));
typedef int    int4v  __attribute__((ext_vector_type(4)));
typedef unsigned int u32;

__device__ __forceinline__ unsigned short f2bf(float f) {
  u32 u = __builtin_bit_cast(u32, f);
  u += 0x7fffu + ((u >> 16) & 1u);                 // RNE (finite inputs)
  return (unsigned short)(u >> 16);
}
__device__ __forceinline__ u32 umin32(u32 a, u32 b) { return a < b ? a : b; }

// Agent scope (sc1): bypass L1 + non-coherent per-XCD L2; serve at IF$.
__device__ __forceinline__ int4v load16_ag(const u32* p) {
  int4v r;
  asm volatile("global_load_dwordx4 %0, %1, off sc1"
               : "=v"(r) : "v"(p) : "memory");
  return r;
}
__device__ __forceinline__ void store4_ag(u32* p, u32 v) {
  asm volatile("global_store_dword %0, %1, off sc1"
               :: "v"(p), "v"(v) : "memory");
}
__device__ __forceinline__ u32 load_tag_wait(const u32* p) {
  u32 r;
  asm volatile("global_load_dword %0, %1, off sc1\n\ts_waitcnt vmcnt(0)"
               : "=v"(r) : "v"(p) : "memory");
  return r;
}

__device__ __forceinline__ float sigf(float z) {
  return __builtin_amdgcn_rcpf(1.f + __expf(-z));
}
__device__ __forceinline__ float tanh_fast(float v) {
  const float e = __expf(-2.f * fabsf(v));
  const float r = (1.f - e) * __builtin_amdgcn_rcpf(1.f + e);
  return copysignf(r, v);
}

extern "C" __global__ void __launch_bounds__(NTHR, 1)
lstm_persistent(const float* __restrict__ x,
                const float* __restrict__ Wk,
                const float* __restrict__ Rk,
                const float* __restrict__ bias,
                float* __restrict__ out,
                u32* __restrict__ hbuf,             // [2][64][512] tagged u32
                u32* __restrict__ tags)             // [4][64][16] cheap, spread
{
  extern __shared__ char smem[];
  unsigned short* wf   = (unsigned short*)smem;            // [nt][kt][lane][8]
  float*          zbuf = (float*)(smem + WF_BYTES);        // [w][nt][16][17]

  const int bid = blockIdx.x;
  const int tid = threadIdx.x;
  const int w   = tid >> 6;
  const int l   = tid & 63;
  const int g   = bid & 3;         // row group on XCD pair {g, g+4}
  const int m   = bid >> 2;        // u-cols 8m..8m+7

  // ---- one-time weight staging into MFMA B-fragment order ----
  for (int i = tid; i < WF_ELEMS; i += NTHR) {
    const int j    = i & 7;
    const int lane = (i >> 3) & 63;
    const int kt   = (i >> 9) % 24;
    const int nt   = (i >> 9) / 24;
    const int k    = kt * 32 + ((lane >> 4) << 3) + j;     // 0..767
    const int n    = nt * 16 + (lane & 15);                // 0..31
    const int zc   = (n >> 3) * Uu + m * 8 + (n & 7);      // gate*512 + u
    const float v  = (k < 256) ? Wk[(size_t)k * G4U + zc]
                               : Rk[(size_t)(k - 256) * G4U + zc];
    wf[i] = f2bf(v);
  }
  __syncthreads();

  // ---- preload x-part weight fragments (kt = 2q+w, q=0..3) ----
  bf16x8 wfx[4][2];
  #pragma unroll
  for (int q = 0; q < 4; ++q)
    #pragma unroll
    for (int nt = 0; nt < 2; ++nt)
      wfx[q][nt] = *(const bf16x8*)(wf + (((nt * 24) + (2 * q + w)) * 64 + l) * 8);

  // ---- combine-role constants (one (row,u) pair per thread) ----
  const int row_c = tid >> 3;                  // 0..15
  const int uu    = tid & 7;
  const int b_out = g * 16 + row_c;
  const int u_out = m * 8 + uu;
  float breg[4];
  #pragma unroll
  for (int gg = 0; gg < 4; ++gg) breg[gg] = bias[gg * Uu + u_out];
  float creg = 0.f;

  // ---- load-role constants (lane-level, MFMA A-fragment) ----
  const int b_ld = g * 16 + (l & 15);
  const int kq   = (l >> 4) * 8;
  const u32* tagp = tags + ((size_t)g * 64 + l) * TAGSTRIDE;  // producer l's line

  for (int t = 0; t < Tt; ++t) {
    // ---- speculative tagged-h loads FIRST (fully overlap the x phase) ----
    const u32* hp = hbuf + ((size_t)(t & 1) * 64 + b_ld) * Uu + kq;
    int4v hf[16];
    #pragma unroll
    for (int q = 0; q < 8; ++q) {
      hf[2 * q]     = load16_ag(hp + (2 * q + w) * 32);
      hf[2 * q + 1] = load16_ag(hp + (2 * q + w) * 32 + 4);
    }

    // ---- x phase: fp32 loads + cvt + 8 MFMAs (kt = 2q+w) ----
    f32x4 aX0 = {0.f, 0.f, 0.f, 0.f};
    f32x4 aX1 = {0.f, 0.f, 0.f, 0.f};
    const float* xp = x + ((size_t)b_ld * Tt + t) * 256 + kq;
    #pragma unroll
    for (int q = 0; q < 4; ++q) {
      const int kt = 2 * q + w;
      const f32x4 v0 = *(const f32x4*)(xp + kt * 32);
      const f32x4 v1 = *(const f32x4*)(xp + kt * 32 + 4);
      int r0, r1, r2, r3;
      asm("v_cvt_pk_bf16_f32 %0, %1, %2" : "=v"(r0) : "v"(v0[0]), "v"(v0[1]));
      asm("v_cvt_pk_bf16_f32 %0, %1, %2" : "=v"(r1) : "v"(v0[2]), "v"(v0[3]));
      asm("v_cvt_pk_bf16_f32 %0, %1, %2" : "=v"(r2) : "v"(v1[0]), "v"(v1[1]));
      asm("v_cvt_pk_bf16_f32 %0, %1, %2" : "=v"(r3) : "v"(v1[2]), "v"(v1[3]));
      const int4v ai = {r0, r1, r2, r3};
      const bf16x8 a = __builtin_bit_cast(bf16x8, ai);
      aX0 = __builtin_amdgcn_mfma_f32_16x16x32_bf16(a, wfx[q][0], aX0, 0, 0, 0);
      aX1 = __builtin_amdgcn_mfma_f32_16x16x32_bf16(a, wfx[q][1], aX1, 0, 0, 0);
    }

    // ---- drain: x loads + speculative h loads + PREV-STEP h stores ----
    asm volatile("s_waitcnt vmcnt(0)" ::: "memory");
    __builtin_amdgcn_sched_barrier(0);
    __syncthreads();              // both waves drained -> h_t provably at IF$
    if (tid == 0)
      store4_ag(tags + ((size_t)g * 64 + m) * TAGSTRIDE, (u32)t);  // cheap tag

    // ---- validate embedded tags; retry via cheap-tag gate ----
    for (;;) {
      u32 m0 = ~0u, m1 = ~0u, m2 = ~0u, m3 = ~0u;
      #pragma unroll
      for (int q = 0; q < 16; ++q) {
        m0 = umin32(m0, (u32)hf[q][0]);
        m1 = umin32(m1, (u32)hf[q][1]);
        m2 = umin32(m2, (u32)hf[q][2]);
        m3 = umin32(m3, (u32)hf[q][3]);
      }
      const u32 mv = umin32(umin32(m0, m1), umin32(m2, m3));
      if (__all((mv >> 16) == (u32)t)) break;      // all words fresh
      // stale: wait on cheap tags (256 B/wave/round), then reload ONCE
      u32 tv;
      do {
        __builtin_amdgcn_s_sleep(1);
        tv = load_tag_wait(tagp);
      } while (!__all(tv >= (u32)t));
      #pragma unroll
      for (int q = 0; q < 8; ++q) {
        hf[2 * q]     = load16_ag(hp + (2 * q + w) * 32);
        hf[2 * q + 1] = load16_ag(hp + (2 * q + w) * 32 + 4);
      }
      asm volatile("s_waitcnt vmcnt(0)" ::: "memory");
      __builtin_amdgcn_sched_barrier(0);
    }

    // ---- h phase: repack + 16 MFMAs on validated data ----
    f32x4 aH0 = {0.f, 0.f, 0.f, 0.f};
    f32x4 aH1 = {0.f, 0.f, 0.f, 0.f};
    #pragma unroll
    for (int q = 0; q < 8; ++q) {
      const int kt = 8 + 2 * q + w;
      const u32 w0 = __builtin_amdgcn_perm((u32)hf[2*q][1],   (u32)hf[2*q][0],   0x05040100u);
      const u32 w1 = __builtin_amdgcn_perm((u32)hf[2*q][3],   (u32)hf[2*q][2],   0x05040100u);
      const u32 w2 = __builtin_amdgcn_perm((u32)hf[2*q+1][1], (u32)hf[2*q+1][0], 0x05040100u);
      const u32 w3 = __builtin_amdgcn_perm((u32)hf[2*q+1][3], (u32)hf[2*q+1][2], 0x05040100u);
      const int4v ai = {(int)w0, (int)w1, (int)w2, (int)w3};
      const bf16x8 a = __builtin_bit_cast(bf16x8, ai);
      const bf16x8 b0 = *(const bf16x8*)(wf + ((0 * 24 + kt) * 64 + l) * 8);
      const bf16x8 b1 = *(const bf16x8*)(wf + ((1 * 24 + kt) * 64 + l) * 8);
      aH0 = __builtin_amdgcn_mfma_f32_16x16x32_bf16(a, b0, aH0, 0, 0, 0);
      aH1 = __builtin_amdgcn_mfma_f32_16x16x32_bf16(a, b1, aH1, 0, 0, 0);
    }

    const f32x4 z0 = aX0 + aH0;
    const f32x4 z1 = aX1 + aH1;

    // ---- cross-wave z reduce through zbuf ----
    __syncthreads();                             // WAR vs previous combine
    {
      float* zb = zbuf + ((w * 2 + 0) * 16 + (l >> 4) * 4) * 17 + (l & 15);
      #pragma unroll
      for (int r = 0; r < 4; ++r) {
        zb[r * 17]           = z0[r];
        zb[r * 17 + 16 * 17] = z1[r];            // nt=1 plane
      }
    }
    __syncthreads();

    // ---- gate math (fp32), cell update ----
    float z[4];
    #pragma unroll
    for (int gg = 0; gg < 4; ++gg) {
      const int n  = gg * 8 + uu;
      const int nt = n >> 4, nc = n & 15;
      z[gg] = zbuf[((0 + nt) * 16 + row_c) * 17 + nc]
            + zbuf[((2 + nt) * 16 + row_c) * 17 + nc]
            + breg[gg];
    }
    const float ig = sigf(z[0]);
    const float fg = sigf(z[1]);
    const float og = sigf(z[3]);
    const float cc = fg * creg + ig * z[2];
    creg = cc;
    const float hh = og * cc;

    // ---- publish: tagged h store, FIRE-AND-FORGET (no ack, no tag hop) ----
    const u32 hw = ((u32)(t + 1) << 16) | (u32)f2bf(hh);
    store4_ag(hbuf + ((size_t)((t + 1) & 1) * 64 + b_out) * Uu + u_out, hw);

    // out store: non-temporal fire-and-forget, off the critical path
    __builtin_nontemporal_store(tanh_fast(hh),
                                &out[((size_t)b_out * Tt + t) * Uu + u_out]);
  }
}

extern "C" void kernel_launch(void* const* d_in, const int* in_sizes, int n_in,
                              void* d_out, int out_size, void* d_ws, size_t ws_size,
                              hipStream_t stream) {
  const float* x    = (const float*)d_in[0];
  const float* Wk   = (const float*)d_in[1];
  const float* Rk   = (const float*)d_in[2];
  const float* bias = (const float*)d_in[3];
  float* out = (float*)d_out;
  u32* hbuf = (u32*)d_ws;
  u32* tags = (u32*)((char*)d_ws + (size_t)2 * 64 * Uu * sizeof(u32));

  // zeroed hbuf == valid tag-0 h_0 = 0 (both parities); cheap tags 0.
  (void)hipMemsetAsync(d_ws, 0,
                       (size_t)2 * 64 * Uu * sizeof(u32)
                         + (size_t)4 * 64 * TAGSTRIDE * sizeof(u32),
                       stream);

  (void)hipFuncSetAttribute((const void*)lstm_persistent,
                            hipFuncAttributeMaxDynamicSharedMemorySize,
                            SMEM_BYTES);

  hipLaunchKernelGGL(lstm_persistent, dim3(NWG), dim3(NTHR), SMEM_BYTES, stream,
                     x, Wk, Rk, bias, out, hbuf, tags);
}

// Round 15
// 2752.270 us; speedup vs baseline: 2.1760x; 2.1760x over previous
//
#include <hip/hip_runtime.h>
#include <stdint.h>

// Persistent-LSTM, round 15: r11 protocol + serial-chain micro-surgery.
// (r14's speculation and r13's coalesced release both regressed; reverted.)
//  - 256 WGs x 128 threads (2 waves). g = bid&3 (rows 16g..16g+15, XCD-pair
//    locality), m = bid>>2 (u-cols 8m..8m+7). hbuf plain bf16 [2][64][512];
//    spread tags [4][64][16]; wave-0-only tag poll + barrier hand-off;
//    release = {h store sc1} -> vmcnt(0) -> s_barrier -> tid0 tag store.
//  - NEW (1) counted-vmcnt poll head: tail order = tag store -> PROBE ->
//    out store; the first tag check waits vmcnt(1) so the probe is certified
//    while the slow HBM out-store ack stays pending (r11 paid that ack in
//    the poll's vmcnt(0) every step).
//  - NEW (2) x register-prefetch one step ahead, issued right after the h
//    data loads; the release vmcnt(0) certifies it for free -> x-phase is
//    pure cvt+MFMA, zero load wait.
//  - NEW (3) zbuf double-buffered by t-parity -> WAR __syncthreads deleted
//    (3 barriers/step instead of 4). Safety: reads of zbuf[p] at step t
//    finish before step t's release s_barrier; next write to zbuf[p] is at
//    t+2, after both waves passed t+1's barriers.
//  - NEW (4) split h drain: vmcnt(12) -> 4 MFMAs -> vmcnt(8) -> 4 MFMAs
//    (counts include 8 x-prefetch loads and a possibly-pending out store,
//    which retire in issue order). sched_barrier(0) after every waitcnt.

#define Tt   1024
#define Uu   512
#define G4U  2048
#define NWG  256
#define NTHR 128
#define TAGSTRIDE 16                               // u32s per tag line (64 B)

#define WF_ELEMS (2 * 24 * 64 * 8)                 // 24576 bf16 = 48 KB
#define WF_BYTES (WF_ELEMS * 2)
#define ZB_PLANE (16 * 17)
#define ZB_HALF  (4 * ZB_PLANE)                    // floats per parity buffer
#define SMEM_BYTES (WF_BYTES + 2 * ZB_HALF * 4)    // 48 KB + 8704 B

typedef short  bf16x8 __attribute__((ext_vector_type(8)));
typedef float  f32x4  __attribute__((ext_vector_type(4)));
typedef int    int4v  __attribute__((ext_vector_type(4)));
typedef unsigned int u32;

__device__ __forceinline__ unsigned short f2bf(float f) {
  u32 u = __builtin_bit_cast(u32, f);
  u += 0x7fffu + ((u >> 16) & 1u);                 // RNE (finite inputs)
  return (unsigned short)(u >> 16);
}

// sc1 = agent scope (IF$); plain = cached (x, read-only).
__device__ __forceinline__ int4v ld16_ag(const unsigned short* p) {
  int4v r;
  asm volatile("global_load_dwordx4 %0, %1, off sc1"
               : "=v"(r) : "v"(p) : "memory");
  return r;
}
__device__ __forceinline__ int4v ld16_nc(const float* p) {
  int4v r;
  asm volatile("global_load_dwordx4 %0, %1, off"
               : "=v"(r) : "v"(p) : "memory");
  return r;
}
__device__ __forceinline__ void store2_ag(unsigned short* p, unsigned short v) {
  asm volatile("global_store_short %0, %1, off sc1"
               :: "v"(p), "v"((u32)v) : "memory");
}
__device__ __forceinline__ void store4_ag(u32* p, u32 v) {
  asm volatile("global_store_dword %0, %1, off sc1"
               :: "v"(p), "v"(v) : "memory");
}

__device__ __forceinline__ float sigf(float z) {
  return __builtin_amdgcn_rcpf(1.f + __expf(-z));
}
__device__ __forceinline__ float tanh_fast(float v) {
  const float e = __expf(-2.f * fabsf(v));
  const float r = (1.f - e) * __builtin_amdgcn_rcpf(1.f + e);
  return copysignf(r, v);
}

extern "C" __global__ void __launch_bounds__(NTHR, 1)
lstm_persistent(const float* __restrict__ x,
                const float* __restrict__ Wk,
                const float* __restrict__ Rk,
                const float* __restrict__ bias,
                float* __restrict__ out,
                unsigned short* __restrict__ hbuf,  // [2][64][512] bf16
                u32* __restrict__ tags)             // [4][64][16] spread
{
  extern __shared__ char smem[];
  unsigned short* wf   = (unsigned short*)smem;            // [nt][kt][lane][8]
  float*          zbuf = (float*)(smem + WF_BYTES);        // [2][w*nt][16][17]

  const int bid = blockIdx.x;
  const int tid = threadIdx.x;
  const int w   = tid >> 6;
  const int l   = tid & 63;
  const int g   = bid & 3;         // row group on XCD pair {g, g+4}
  const int m   = bid >> 2;        // u-cols 8m..8m+7

  // ---- one-time weight staging into MFMA B-fragment order ----
  for (int i = tid; i < WF_ELEMS; i += NTHR) {
    const int j    = i & 7;
    const int lane = (i >> 3) & 63;
    const int kt   = (i >> 9) % 24;
    const int nt   = (i >> 9) / 24;
    const int k    = kt * 32 + ((lane >> 4) << 3) + j;     // 0..767
    const int n    = nt * 16 + (lane & 15);                // 0..31
    const int zc   = (n >> 3) * Uu + m * 8 + (n & 7);      // gate*512 + u
    const float v  = (k < 256) ? Wk[(size_t)k * G4U + zc]
                               : Rk[(size_t)(k - 256) * G4U + zc];
    wf[i] = f2bf(v);
  }
  __syncthreads();

  // ---- preload x-part weight fragments (kt = 2q+w, q=0..3) ----
  bf16x8 wfx[4][2];
  #pragma unroll
  for (int q = 0; q < 4; ++q)
    #pragma unroll
    for (int nt = 0; nt < 2; ++nt)
      wfx[q][nt] = *(const bf16x8*)(wf + (((nt * 24) + (2 * q + w)) * 64 + l) * 8);

  // ---- combine-role constants (one (row,u) pair per thread) ----
  const int row_c = tid >> 3;                  // 0..15
  const int uu    = tid & 7;
  const int b_out = g * 16 + row_c;
  const int u_out = m * 8 + uu;
  float breg[4];
  #pragma unroll
  for (int gg = 0; gg < 4; ++gg) breg[gg] = bias[gg * Uu + u_out];
  float creg = 0.f;

  // ---- load-role constants (lane-level, MFMA A-fragment) ----
  const int b_ld = g * 16 + (l & 15);
  const int kq   = (l >> 4) * 8;
  const u32* tagp = tags + ((size_t)g * 64 + l) * TAGSTRIDE;  // producer l's line

  // ---- pre-loop: prefetch x(t=0); issue + drain initial probe ----
  int4v xv[4][2];
  {
    const float* xp0 = x + ((size_t)b_ld * Tt + 0) * 256 + kq;
    #pragma unroll
    for (int q = 0; q < 4; ++q) {
      const int kt = 2 * q + w;
      xv[q][0] = ld16_nc(xp0 + kt * 32);
      xv[q][1] = ld16_nc(xp0 + kt * 32 + 4);
    }
  }
  u32 tv = 0;
  if (w == 0)
    asm volatile("global_load_dword %0, %1, off sc1"
                 : "=v"(tv) : "v"(tagp) : "memory");
  asm volatile("s_waitcnt vmcnt(0)" ::: "memory");
  __builtin_amdgcn_sched_barrier(0);

  for (int t = 0; t < Tt; ++t) {
    // ---- x phase: pure cvt + 8 MFMAs (x regs prefetched & certified) ----
    f32x4 aX0 = {0.f, 0.f, 0.f, 0.f};
    f32x4 aX1 = {0.f, 0.f, 0.f, 0.f};
    #pragma unroll
    for (int q = 0; q < 4; ++q) {
      const f32x4 v0 = __builtin_bit_cast(f32x4, xv[q][0]);
      const f32x4 v1 = __builtin_bit_cast(f32x4, xv[q][1]);
      int r0, r1, r2, r3;
      asm("v_cvt_pk_bf16_f32 %0, %1, %2" : "=v"(r0) : "v"(v0[0]), "v"(v0[1]));
      asm("v_cvt_pk_bf16_f32 %0, %1, %2" : "=v"(r1) : "v"(v0[2]), "v"(v0[3]));
      asm("v_cvt_pk_bf16_f32 %0, %1, %2" : "=v"(r2) : "v"(v1[0]), "v"(v1[1]));
      asm("v_cvt_pk_bf16_f32 %0, %1, %2" : "=v"(r3) : "v"(v1[2]), "v"(v1[3]));
      const int4v ai = {r0, r1, r2, r3};
      const bf16x8 a = __builtin_bit_cast(bf16x8, ai);
      aX0 = __builtin_amdgcn_mfma_f32_16x16x32_bf16(a, wfx[q][0], aX0, 0, 0, 0);
      aX1 = __builtin_amdgcn_mfma_f32_16x16x32_bf16(a, wfx[q][1], aX1, 0, 0, 0);
    }

    // ---- acquire: wave 0 checks prior probe via COUNTED vmcnt(1) ----
    // (outstanding, issue order: [tag store (lane0) <], probe, out store ->
    //  in-order retire means vmcnt(1) certifies the probe while the slow
    //  out-store ack stays pending)
    if (w == 0) {
      asm volatile("s_waitcnt vmcnt(1)" ::: "memory");
      __builtin_amdgcn_sched_barrier(0);
      while (!__all(tv >= (u32)t)) {
        __builtin_amdgcn_s_sleep(1);
        asm volatile("global_load_dword %0, %1, off sc1\n\ts_waitcnt vmcnt(0)"
                     : "=v"(tv) : "v"(tagp) : "memory");
        __builtin_amdgcn_sched_barrier(0);
      }
    }
    __builtin_amdgcn_s_barrier();                // hand-off: tags observed
    __builtin_amdgcn_sched_barrier(0);

    // ---- h data loads (after tag pass), then x prefetch for t+1 ----
    const unsigned short* hrow =
        hbuf + ((size_t)(t & 1) * 64 + b_ld) * Uu + kq;
    int4v hf[8];
    #pragma unroll
    for (int q = 0; q < 8; ++q)
      hf[q] = ld16_ag(hrow + (2 * q + w) * 32);
    {
      const int tn = (t + 1 < Tt) ? t + 1 : t;   // clamp: avoid OOB read
      const float* xpn = x + ((size_t)b_ld * Tt + tn) * 256 + kq;
      #pragma unroll
      for (int q = 0; q < 4; ++q) {
        const int kt = 2 * q + w;
        xv[q][0] = ld16_nc(xpn + kt * 32);
        xv[q][1] = ld16_nc(xpn + kt * 32 + 4);
      }
    }

    // ---- split drain + h MFMAs (h loads are the oldest 8 in the queue) ----
    f32x4 aH0 = {0.f, 0.f, 0.f, 0.f};
    f32x4 aH1 = {0.f, 0.f, 0.f, 0.f};
    asm volatile("s_waitcnt vmcnt(12)" ::: "memory");  // hf[0..3] done
    __builtin_amdgcn_sched_barrier(0);
    #pragma unroll
    for (int q = 0; q < 4; ++q) {
      const int kt = 8 + 2 * q + w;
      const bf16x8 a = __builtin_bit_cast(bf16x8, hf[q]);
      const bf16x8 b0 = *(const bf16x8*)(wf + ((0 * 24 + kt) * 64 + l) * 8);
      const bf16x8 b1 = *(const bf16x8*)(wf + ((1 * 24 + kt) * 64 + l) * 8);
      aH0 = __builtin_amdgcn_mfma_f32_16x16x32_bf16(a, b0, aH0, 0, 0, 0);
      aH1 = __builtin_amdgcn_mfma_f32_16x16x32_bf16(a, b1, aH1, 0, 0, 0);
    }
    asm volatile("s_waitcnt vmcnt(8)" ::: "memory");   // hf[4..7] done
    __builtin_amdgcn_sched_barrier(0);
    #pragma unroll
    for (int q = 4; q < 8; ++q) {
      const int kt = 8 + 2 * q + w;
      const bf16x8 a = __builtin_bit_cast(bf16x8, hf[q]);
      const bf16x8 b0 = *(const bf16x8*)(wf + ((0 * 24 + kt) * 64 + l) * 8);
      const bf16x8 b1 = *(const bf16x8*)(wf + ((1 * 24 + kt) * 64 + l) * 8);
      aH0 = __builtin_amdgcn_mfma_f32_16x16x32_bf16(a, b0, aH0, 0, 0, 0);
      aH1 = __builtin_amdgcn_mfma_f32_16x16x32_bf16(a, b1, aH1, 0, 0, 0);
    }

    const f32x4 z0 = aX0 + aH0;
    const f32x4 z1 = aX1 + aH1;

    // ---- z reduce through parity-double-buffered zbuf (1 barrier) ----
    float* zb = zbuf + (t & 1) * ZB_HALF;
    {
      float* zw = zb + ((w * 2 + 0) * 16 + (l >> 4) * 4) * 17 + (l & 15);
      #pragma unroll
      for (int r = 0; r < 4; ++r) {
        zw[r * 17]           = z0[r];
        zw[r * 17 + 16 * 17] = z1[r];            // nt=1 plane
      }
    }
    __syncthreads();

    // ---- gate math (fp32), cell update ----
    float z[4];
    #pragma unroll
    for (int gg = 0; gg < 4; ++gg) {
      const int n  = gg * 8 + uu;
      const int nt = n >> 4, nc = n & 15;
      z[gg] = zb[((0 + nt) * 16 + row_c) * 17 + nc]
            + zb[((2 + nt) * 16 + row_c) * 17 + nc]
            + breg[gg];
    }
    const float ig = sigf(z[0]);
    const float fg = sigf(z[1]);
    const float og = sigf(z[3]);
    const float cc = fg * creg + ig * z[2];
    creg = cc;
    const float hh = og * cc;

    // ---- release: h store -> ack -> barrier -> tag -> probe -> out ----
    store2_ag(hbuf + ((size_t)((t + 1) & 1) * 64 + b_out) * Uu + u_out,
              f2bf(hh));
    asm volatile("s_waitcnt vmcnt(0)" ::: "memory");   // h ack (+x-pf certified)
    __builtin_amdgcn_sched_barrier(0);
    __builtin_amdgcn_s_barrier();                // all 128 producers drained
    __builtin_amdgcn_sched_barrier(0);
    if (tid == 0)
      store4_ag(tags + ((size_t)g * 64 + m) * TAGSTRIDE, (u32)(t + 1));
    if (w == 0)
      asm volatile("global_load_dword %0, %1, off sc1"
                   : "=v"(tv) : "v"(tagp) : "memory");  // next probe BEFORE out
    {
      const float ov = tanh_fast(hh);
      float* op = out + ((size_t)b_out * Tt + t) * Uu + u_out;
      asm volatile("global_store_dword %0, %1, off nt"
                   :: "v"(op), "v"(ov) : "memory");     // slow ack stays behind probe
    }
  }
}

extern "C" void kernel_launch(void* const* d_in, const int* in_sizes, int n_in,
                              void* d_out, int out_size, void* d_ws, size_t ws_size,
                              hipStream_t stream) {
  const float* x    = (const float*)d_in[0];
  const float* Wk   = (const float*)d_in[1];
  const float* Rk   = (const float*)d_in[2];
  const float* bias = (const float*)d_in[3];
  float* out = (float*)d_out;
  unsigned short* hbuf = (unsigned short*)d_ws;
  u32* tags = (u32*)((char*)d_ws + (size_t)2 * 64 * Uu * sizeof(unsigned short));

  // zeroed hbuf = h_0 = 0 (both parities); tags 0 = "h_0 published".
  (void)hipMemsetAsync(d_ws, 0,
                       (size_t)2 * 64 * Uu * sizeof(unsigned short)
                         + (size_t)4 * 64 * TAGSTRIDE * sizeof(u32),
                       stream);

  (void)hipFuncSetAttribute((const void*)lstm_persistent,
                            hipFuncAttributeMaxDynamicSharedMemorySize,
                            SMEM_BYTES);

  hipLaunchKernelGGL(lstm_persistent, dim3(NWG), dim3(NTHR), SMEM_BYTES, stream,
                     x, Wk, Rk, bias, out, hbuf, tags);
}